// Round 7
// baseline (494.827 us; speedup 1.0000x reference)
//
#include <hip/hip_runtime.h>
#include <hip/hip_bf16.h>
#include <stdint.h>

#define BB 32
#define GG 100
#define AA 8400
#define TPB 256
#define NCH 33                         // ceil(8400/256) chunks per image
#define TKB 512                        // kB block size (8 waves)
#define BA (BB*AA)
#define NG (BB*GG)
#define PCAP 8416                      // positives cap (>= AA, cannot overflow)
#define GCAP 128                       // geo cap (provably <= 75 per gt)
#define SCAP (GG*10)                   // selection slots per image (g*10+k)

typedef __hip_bfloat16 bf16;

struct P {
  const void *outs, *labs, *ss;
  float4 *box4, *meta4, *gtb, *gtc;   // per-anchor box/meta; per-gt box/center
  float4 *cbox;                       // per-image compacted fg pred boxes
  uint32_t *cpk;                      // compacted packed (xc,yc,lvl)
  float *carea, *cpcc;                // compacted pred area / cls-cost
  int   *sel_a;                       // [BB][SCAP] selected anchor id, -1 empty
  float *sel_iou;                     // [BB][SCAP] its iou
  float *pb, *pf;                     // per-image BCE / fg partials
  int *gmax, *nfg, *chunkcnt, *ticket;
  float *out;
};

// runtime input-dtype detection: strides[0]==8.0
// f32 word 0x41000000 ; bf16 pair (8.0,8.0) 0x41004100
__device__ __forceinline__ int dtypeFlag(const void* ss){
  return (((const uint32_t*)ss)[0] == 0x41000000u) ? 1 : 0;
}
__device__ __forceinline__ float ld(const void* p, int i, int isf32){
  return isf32 ? ((const float*)p)[i] : __bfloat162float(((const bf16*)p)[i]);
}
// analytic anchor geometry (exact: ints + pow2 strides exact in f32/bf16)
__device__ __forceinline__ void ageom(int a, float& xc, float& yc, float& r){
  int x, y, s;
  if (a < 6400){ x = a % 80; y = a / 80; s = 8; }
  else if (a < 8000){ int q = a - 6400; x = q % 40; y = q / 40; s = 16; }
  else { int q = a - 8000; x = q % 20; y = q / 20; s = 32; }
  float fs = (float)s;
  xc = ((float)x + 0.5f) * fs;
  yc = ((float)y + 0.5f) * fs;
  r  = 2.5f * fs;
}
// pack integer center + level: xc(10) | yc(10)<<10 | lvl<<20
__device__ __forceinline__ uint32_t apack2(int a){
  int x, y, s, lvl;
  if (a < 6400){ x = a % 80; y = a / 80; s = 8; lvl = 0; }
  else if (a < 8000){ int q = a - 6400; x = q % 40; y = q / 40; s = 16; lvl = 1; }
  else { int q = a - 8000; x = q % 20; y = q / 20; s = 32; lvl = 2; }
  return (uint32_t)(x*s + s/2) | ((uint32_t)(y*s + s/2) << 10) | ((uint32_t)lvl << 20);
}
// exact inverse: packed -> anchor id
__device__ __forceinline__ int adecode(uint32_t u){
  int xi = u & 1023, yi = (u >> 10) & 1023, lvl = (int)(u >> 20);
  int sh = 3 + lvl, hf = 4 << lvl;
  int ax = (xi - hf) >> sh, ay = (yi - hf) >> sh;
  if (lvl == 0) return ay*80 + ax;
  if (lvl == 1) return 6400 + ay*40 + ax;
  return 8000 + ay*20 + ax;
}

// ---- kA: gt structs (self-computed) + per-anchor staging + fg + chunk count
// v8: cnt-zeroing removed (cnt array deleted); inits sel_a slots to -1 and
// the kC ticket instead.
__global__ __launch_bounds__(TPB) void kA(P p){
  __shared__ float4 s_gtb[GG], s_gtc[GG];
  __shared__ float s_o[TPB*6];
  __shared__ int s_w[4];
  __shared__ int s_ng;
  int t = threadIdx.x;
  int c = blockIdx.x, b = blockIdx.y;
  int isf = dtypeFlag(p.ss);
  if (t == 0) s_ng = 0;
  if (c == 0 && b == 0 && t == 0) *p.ticket = 0;   // for fused kC finisher
  {
    int s = c*TPB + t;
    if (s < SCAP) p.sel_a[b*SCAP + s] = -1;        // empty slot marker
  }
  int nel = min(TPB*6, AA*6 - c*(TPB*6));      // floats in this chunk
  if (isf){
    const float4* src = (const float4*)((const float*)p.outs + (size_t)b*AA*6 + (size_t)c*(TPB*6));
    float4* dst = (float4*)s_o;
    for (int i = t; i < nel/4; i += TPB) dst[i] = src[i];
  } else {
    const uint4* src = (const uint4*)((const bf16*)p.outs + (size_t)b*AA*6 + (size_t)c*(TPB*6));
    for (int i = t; i < nel/8; i += TPB){
      uint4 u = src[i];
      int o = i*8;
      s_o[o+0]=__uint_as_float(u.x<<16); s_o[o+1]=__uint_as_float(u.x&0xffff0000u);
      s_o[o+2]=__uint_as_float(u.y<<16); s_o[o+3]=__uint_as_float(u.y&0xffff0000u);
      s_o[o+4]=__uint_as_float(u.z<<16); s_o[o+5]=__uint_as_float(u.z&0xffff0000u);
      s_o[o+6]=__uint_as_float(u.w<<16); s_o[o+7]=__uint_as_float(u.w&0xffff0000u);
    }
  }
  __syncthreads();
  if (t < GG){
    int i = b*GG + t;
    float l0 = ld(p.labs, i*5  , isf);
    float gcx= ld(p.labs, i*5+1, isf);
    float gcy= ld(p.labs, i*5+2, isf);
    float gw = ld(p.labs, i*5+3, isf);
    float gh = ld(p.labs, i*5+4, isf);
    int valid = (l0+gcx+gcy+gw+gh) > 0.f;
    float4 vb = make_float4(gcx-gw*0.5f, gcy-gh*0.5f, gcx+gw*0.5f, gcy+gh*0.5f);
    float4 vc = make_float4(gcx, gcy, gw*gh, valid ? 1.f : 0.f);
    s_gtb[t] = vb; s_gtc[t] = vc;
    if (c == 0){ p.gtb[i] = vb; p.gtc[i] = vc; }
    if (valid) atomicMax(&s_ng, t+1);
  }
  __syncthreads();
  int ng = s_ng;
  if (c == 0 && t == 0) p.gmax[b] = ng;
  int a = c*TPB + t;
  int fg = 0;
  if (a < AA){
    float cx=s_o[t*6], cy=s_o[t*6+1], w=s_o[t*6+2], h=s_o[t*6+3], ob=s_o[t*6+4], cl=s_o[t*6+5];
    int idx = b*AA + a;
    p.box4[idx] = make_float4(cx-w*0.5f, cy-h*0.5f, cx+w*0.5f, cy+h*0.5f);
    float so = 1.f/(1.f+expf(-ob));
    float sc = 1.f/(1.f+expf(-cl));
    float pcc = -logf(sqrtf(sc*so) + 1e-9f);
    float xc, yc, r; ageom(a, xc, yc, r);
    for (int g = 0; g < ng; ++g){
      float4 gb = s_gtb[g], gc = s_gtc[g];
      bool inb = (xc>gb.x)&&(xc<gb.z)&&(yc>gb.y)&&(yc<gb.w);
      bool inc = (fabsf(xc-gc.x)<r)&&(fabsf(yc-gc.y)<r);
      fg |= (gc.w != 0.f) && (inb||inc);
    }
    p.meta4[idx] = make_float4(w*h, pcc, fg ? 1.f : 0.f, cl);
  }
  int lane = t & 63, wid = t >> 6;
  unsigned long long m = __ballot(fg);
  if (lane == 0) s_w[wid] = __popcll(m);
  __syncthreads();
  if (t == 0) p.chunkcnt[b*NCH + c] = s_w[0]+s_w[1]+s_w[2]+s_w[3];
}

// ---- kE: parallel order-preserving fg compaction (one block per chunk) -----
__global__ __launch_bounds__(TPB) void kE(P p){
  __shared__ int s_off;
  __shared__ int s_w[4];
  int t = threadIdx.x, c = blockIdx.x, b = blockIdx.y;
  int lane = t & 63, wid = t >> 6;
  if (wid == 0){
    int v = (lane < c) ? p.chunkcnt[b*NCH + lane] : 0;   // c <= 32 < 64 lanes
#pragma unroll
    for (int off=32; off; off>>=1) v += __shfl_xor(v, off);
    if (lane == 0) s_off = v;
  }
  int a = c*TPB + t;
  float4 mt = make_float4(0,0,0,0);
  int fg = 0;
  if (a < AA){ mt = p.meta4[b*AA+a]; fg = (mt.z != 0.f) ? 1 : 0; }
  unsigned long long m = __ballot(fg);
  int rank = __popcll(m & ((1ull<<lane)-1ull));
  if (lane == 0) s_w[wid] = __popcll(m);
  __syncthreads();
  int off = s_off;
  for (int w2 = 0; w2 < wid; ++w2) off += s_w[w2];
  if (fg){
    int pos = off + rank;
    p.cbox [b*AA+pos] = p.box4[b*AA+a];
    p.cpk  [b*AA+pos] = apack2(a);
    p.carea[b*AA+pos] = mt.x;
    p.cpcc [b*AA+pos] = mt.y;
  }
  if (c == NCH-1 && t == 0)
    p.nfg[b] = s_off + s_w[0]+s_w[1]+s_w[2]+s_w[3];
}

// ---- kB: per-(b,g) dyn_k + selection -------------------------------------
// v6 core (unchanged, passed absmax 0 r5/r6). v8 delta: output is now a
// DETERMINISTIC slot write sel_a/sel_iou[b][g*10+k] instead of cnt atomics +
// racy miou. No global atomics left in kB.
__global__ __launch_bounds__(TKB) void kB(P p){
  __shared__ float s_pos[PCAP];
  __shared__ float s_gcost[GCAP];
  __shared__ int   s_gpos[GCAP];
  __shared__ int   s_pcnt, s_gcnt;
  int t = threadIdx.x;
  int lane = t & 63, wid = t >> 6;
  int item = blockIdx.x;
  int b = item / GG, g = item - b*GG;       // balanced across XCDs
  if (t == 0){ s_pcnt = 0; s_gcnt = 0; }
  float4 gc = p.gtc[b*GG+g];
  if (gc.w == 0.f) return;                  // uniform exit, pre-barrier
  float4 gb = p.gtb[b*GG+g];
  float glx=gb.x, gly=gb.y, ghx=gb.z, ghy=gb.w, gcx=gc.x, gcy=gc.y, ga=gc.z;
  int base = b*AA;
  int nfg = p.nfg[b];
  unsigned long long lmlt = (1ull<<lane) - 1ull;
  __syncthreads();                          // s_pcnt/s_gcnt init visible

  // main screen: ~30 VALU/pair, 20B/pair steady; heavy math only on hits
  int nIt = (nfg + TKB - 1) / TKB;
  for (int it = 0; it < nIt; ++it){
    int pos = it*TKB + t;
    bool vld = pos < nfg;
    bool ovl = false, geo = false;
    float v = 0.f, cst = 0.f;
    if (vld){
      uint32_t u = p.cpk[base+pos];
      float xc = (float)(u & 1023u), yc = (float)((u>>10)&1023u);
      float r  = (float)(20u << (u>>20));
      bool inb = (xc>glx)&&(xc<ghx)&&(yc>gly)&&(yc<ghy);
      geo = inb && (fabsf(xc-gcx)<r) && (fabsf(yc-gcy)<r);
      float4 bx = p.cbox[base+pos];
      float tlx=fmaxf(glx,bx.x), tly=fmaxf(gly,bx.y);
      float brx=fminf(ghx,bx.z), bry=fminf(ghy,bx.w);
      float iw=brx-tlx, ih=bry-tly;
      ovl = (iw>0.f)&&(ih>0.f);
      if (ovl | geo){
        float area = p.carea[base+pos];
        float inter = fmaxf(iw,0.f)*fmaxf(ih,0.f);
        v = inter/(ga + area - inter + 1e-12f);
        if (geo) cst = p.cpcc[base+pos] + 3.f*(-logf(v+1e-8f));
      }
    }
    unsigned long long m1 = __ballot(ovl);
    if (m1){
      int ldr = (int)(__ffsll(m1)-1);
      int off;
      if (lane == ldr) off = atomicAdd(&s_pcnt, __popcll(m1));
      off = __shfl(off, ldr);
      if (ovl) s_pos[off + __popcll(m1 & lmlt)] = v;
    }
    unsigned long long m2 = __ballot(geo);
    if (m2){
      int ldr = (int)(__ffsll(m2)-1);
      int off;
      if (lane == ldr) off = atomicAdd(&s_gcnt, __popcll(m2));
      off = __shfl(off, ldr);
      if (geo){
        int q = off + __popcll(m2 & lmlt);
        s_gcost[q] = cst; s_gpos[q] = pos;
      }
    }
  }
  __syncthreads();
  if (wid) return;                          // 7 waves done; wave 0 selects

  int pcnt = s_pcnt, gcnt = s_gcnt;         // gcnt <= 75 < GCAP

  // dk: top-10 positives by pop-extraction over s_pos (values only;
  // descending add order == jnp top_k sum order; zeros add exactly 0)
  float lmax = -1.f;
  for (int i = lane; i < pcnt; i += 64) lmax = fmaxf(lmax, s_pos[i]);
  float sum = 0.f;
  for (int k = 0; k < 10; ++k){
    float gv = lmax;
#pragma unroll
    for (int off=32; off; off>>=1) gv = fmaxf(gv, __shfl_xor(gv, off));
    if (gv <= 0.f) break;
    sum += gv;
    unsigned long long ms = __ballot(lmax == gv);
    if ((int)(__ffsll(ms)-1) == lane){      // unique owner: remove 1 instance
      bool fnd = false; float nl = -1.f;
      for (int i = lane; i < pcnt; i += 64){
        float vv = s_pos[i];
        if (!fnd && vv == gv){ fnd = true; vv = -1.f; s_pos[i] = vv; }
        nl = fmaxf(nl, vv);
      }
      lmax = nl;
    }
  }
  int dk = (int)sum; if (dk<1) dk=1; if (dk>10) dk=10;

  // selection among geo (<=2 entries/lane; all geo < all non-geo cost)
  float c0=3.0e38f, c1=3.0e38f; int p0=0x7fffffff, p1=0x7fffffff;
  if (lane < gcnt){ c0 = s_gcost[lane]; p0 = s_gpos[lane]; }
  if (lane+64 < gcnt){ c1 = s_gcost[lane+64]; p1 = s_gpos[lane+64]; }
  if (c1 < c0 || (c1==c0 && p1<p0)){
    float tc=c0; c0=c1; c1=tc; int tp=p0; p0=p1; p1=tp;
  }
  int mysel = -1, take = 0;
  for (int k = 0; k < dk; ++k){
    float gv=c0; int gi=p0;
#pragma unroll
    for (int off=32; off; off>>=1){
      float ov=__shfl_xor(gv,off); int oi=__shfl_xor(gi,off);
      if (ov<gv || (ov==gv && oi<gi)){ gv=ov; gi=oi; }
    }
    if (gv >= 2.9e38f) break;               // geo exhausted
    if (lane == k) mysel = gi;
    take++;
    if (c0==gv && p0==gi){ c0=c1; p0=p1; c1=3.0e38f; p1=0x7fffffff; }
  }

  // rare fallback: need (dk-take) non-geo picks; exact k-th smallest via
  // repeated rescan excluding previous picks by strict lex >
  float lastc = -3.0e38f; int lastp = -1;
  for (int k = take; k < dk; ++k){
    float bc = 3.0e38f; int bp = 0x7fffffff;
    int n64 = (nfg + 63) >> 6;
    for (int it = 0; it < n64; ++it){
      int pos = (it<<6) + lane;
      if (pos < nfg){
        uint32_t u = p.cpk[base+pos];
        float xc = (float)(u & 1023u), yc = (float)((u>>10)&1023u);
        float r  = (float)(20u << (u>>20));
        bool inb = (xc>glx)&&(xc<ghx)&&(yc>gly)&&(yc<ghy);
        bool geo2 = inb && (fabsf(xc-gcx)<r) && (fabsf(yc-gcy)<r);
        if (!geo2){
          float4 bx = p.cbox[base+pos];
          float tlx=fmaxf(glx,bx.x), tly=fmaxf(gly,bx.y);
          float brx=fminf(ghx,bx.z), bry=fminf(ghy,bx.w);
          float iw=fmaxf(brx-tlx,0.f), ih=fmaxf(bry-tly,0.f);
          float inter=iw*ih;
          float area = p.carea[base+pos];
          float v = inter/(ga + area - inter + 1e-12f);
          float cst = p.cpcc[base+pos] + 3.f*(-logf(v+1e-8f)) + 100000.f;
          bool gt = (cst > lastc) || (cst == lastc && pos > lastp);
          bool lt = (cst < bc)   || (cst == bc   && pos < bp);
          if (gt && lt){ bc = cst; bp = pos; }
        }
      }
    }
#pragma unroll
    for (int off=32; off; off>>=1){
      float ov=__shfl_xor(bc,off); int oi=__shfl_xor(bp,off);
      if (ov<bc || (ov==bc && oi<bp)){ bc=ov; bp=oi; }
    }
    if (bc >= 2.9e38f) break;               // candidates exhausted
    if (lane == k) mysel = bp;
    lastc = bc; lastp = bp;
  }

  if (mysel >= 0){                          // lanes 0..dk-1 hold selections
    int pos = mysel;
    float4 bx = p.cbox[base+pos];
    float area = p.carea[base+pos];
    int a = adecode(p.cpk[base+pos]);
    float tlx=fmaxf(glx,bx.x), tly=fmaxf(gly,bx.y);
    float brx=fminf(ghx,bx.z), bry=fminf(ghy,bx.w);
    float iw=fmaxf(brx-tlx,0.f), ih=fmaxf(bry-tly,0.f);
    float inter=iw*ih;
    float iou=inter/(ga + area - inter + 1e-12f);
    int slot = b*SCAP + g*10 + lane;        // deterministic, no atomics
    p.sel_a [slot] = a;
    p.sel_iou[slot] = iou;
  }
}

// ---- kC: selection-list conflict resolution + BCE + fused finalize --------
// v8: replaces the 268800-anchor scan (r6 kCD: 66us @ 7% VALU, 7% occupancy,
// 1.3MB fetch -- structurally slow for reasons the body arithmetic cannot
// explain). Processes ONLY the <=1000 selection slots per image: counts per
// anchor derive from the slot list (== old cnt), owner = min-slot occurrence
// (deterministic), cnt>1 recompute verbatim from r6. 32 blocks; kD fused via
// ticket (32 fences @ ~12ns measured r5->r6 = ~0.4us, vs a whole dispatch).
// NOTE: global sum order changes (per-image slots vs per-256-anchor blocks);
// absmax may become small-nonzero for the first time.
__global__ __launch_bounds__(TPB) void kC(P p){
  __shared__ int   s_a[SCAP];
  __shared__ float s_iou[SCAP];
  __shared__ float s_b[4], s_f[4];
  __shared__ int s_last;
  int t = threadIdx.x, b = blockIdx.x;
  int ng = p.gmax[b];
  int ns = ng*10;                           // used slot range
  for (int i = t; i < ns; i += TPB){
    s_a[i]   = p.sel_a [b*SCAP + i];
    s_iou[i] = p.sel_iou[b*SCAP + i];
  }
  __syncthreads();
  float bce = 0.f, fgv = 0.f;
  for (int i = t; i < ns; i += TPB){
    int a = s_a[i];
    if (a < 0) continue;
    // owner check: no earlier slot holds this anchor
    bool owner = true;
    for (int j = 0; j < i; ++j) if (s_a[j] == a){ owner = false; break; }
    if (!owner) continue;
    int cgt = 1;
    for (int j = i+1; j < ns; ++j) cgt += (s_a[j] == a);
    float4 mt = p.meta4[b*AA + a];
    float iouv;
    if (cgt == 1){ iouv = s_iou[i]; }
    else {
      // verbatim r6 conflicted-anchor recompute (first-index argmin)
      float4 bx = p.box4[b*AA + a];
      float xc,yc,r; ageom(a,xc,yc,r);
      float best=3.9e38f, biou=0.f;
      for (int g2=0; g2<ng; ++g2){
        float4 gbb = p.gtb[b*GG+g2], gcc = p.gtc[b*GG+g2];
        float cost, iou2 = 0.f;
        if (gcc.w != 0.f){
          float tlx=fmaxf(gbb.x,bx.x), tly=fmaxf(gbb.y,bx.y);
          float brx=fminf(gbb.z,bx.z), bry=fminf(gbb.w,bx.w);
          float iw=fmaxf(brx-tlx,0.f), ih=fmaxf(bry-tly,0.f);
          float inter=iw*ih;
          iou2 = inter/(gcc.z + mt.x - inter + 1e-12f);
          bool inb=(xc>gbb.x)&&(xc<gbb.z)&&(yc>gbb.y)&&(yc<gbb.w);
          bool inc=(fabsf(xc-gcc.x)<r)&&(fabsf(yc-gcc.y)<r);
          cost = mt.y + 3.f*(-logf(iou2+1e-8f)) + ((inb&&inc)?0.f:100000.f);
        } else cost = 1e9f;
        if (cost < best){ best=cost; biou=iou2; }
      }
      iouv = biou;
    }
    float z = mt.w;
    float e = expf(-fabsf(z));
    float spz = fmaxf(z,0.f)+log1pf(e);
    float spn = fmaxf(-z,0.f)+log1pf(e);
    bce += iouv*spn + (1.f-iouv)*spz;
    fgv += 1.f;
  }
  // block reduce -> per-image partials
  int lane = t & 63, wid = t >> 6;
#pragma unroll
  for (int off=32; off; off>>=1){
    bce += __shfl_xor(bce, off);
    fgv += __shfl_xor(fgv, off);
  }
  if (lane==0){ s_b[wid]=bce; s_f[wid]=fgv; }
  __syncthreads();
  if (t==0){
    p.pb[b] = s_b[0]+s_b[1]+s_b[2]+s_b[3];
    p.pf[b] = s_f[0]+s_f[1]+s_f[2]+s_f[3];
    __threadfence();                       // publish partials (device scope)
    int old = atomicAdd(p.ticket, 1);
    s_last = (old == BB-1) ? 1 : 0;
  }
  __syncthreads();
  if (s_last && t < 64){
    __threadfence();                       // acquire all partials
    float sb = (t < BB) ? p.pb[t] : 0.f;
    float sf = (t < BB) ? p.pf[t] : 0.f;
#pragma unroll
    for (int off=32; off; off>>=1){
      sb += __shfl_xor(sb, off);
      sf += __shfl_xor(sf, off);
    }
    if (t==0) p.out[0] = sb / fmaxf(sf, 1.f);
  }
}

extern "C" void kernel_launch(void* const* d_in, const int* in_sizes, int n_in,
                              void* d_out, int out_size, void* d_ws, size_t ws_size,
                              hipStream_t stream) {
  P p;
  p.outs = d_in[0];
  p.labs = d_in[1];
  p.ss   = d_in[4];
  char* w = (char*)d_ws;
  p.box4  = (float4*)w; w += (size_t)BA*sizeof(float4);
  p.meta4 = (float4*)w; w += (size_t)BA*sizeof(float4);
  p.cbox  = (float4*)w; w += (size_t)BA*sizeof(float4);
  p.gtb   = (float4*)w; w += (size_t)NG*sizeof(float4);
  p.gtc   = (float4*)w; w += (size_t)NG*sizeof(float4);
  p.cpk   = (uint32_t*)w; w += (size_t)BA*sizeof(uint32_t);
  p.carea = (float*)w;  w += (size_t)BA*sizeof(float);
  p.cpcc  = (float*)w;  w += (size_t)BA*sizeof(float);
  p.sel_a = (int*)w;    w += (size_t)BB*SCAP*sizeof(int);
  p.sel_iou=(float*)w;  w += (size_t)BB*SCAP*sizeof(float);
  p.gmax  = (int*)w;    w += (size_t)BB*sizeof(int);
  p.nfg   = (int*)w;    w += (size_t)BB*sizeof(int);
  p.chunkcnt = (int*)w; w += (size_t)BB*NCH*sizeof(int);
  p.pb    = (float*)w;  w += (size_t)BB*sizeof(float);
  p.pf    = (float*)w;  w += (size_t)BB*sizeof(float);
  p.ticket= (int*)w;    w += sizeof(int);
  p.out   = (float*)d_out;

  kA<<<dim3(NCH, BB), TPB, 0, stream>>>(p);
  kE<<<dim3(NCH, BB), TPB, 0, stream>>>(p);
  kB<<<BB*GG, TKB, 0, stream>>>(p);
  kC<<<BB, TPB, 0, stream>>>(p);
}

// Round 8
// 417.679 us; speedup vs baseline: 1.1847x; 1.1847x over previous
//
#include <hip/hip_runtime.h>
#include <hip/hip_bf16.h>
#include <stdint.h>

#define BB 32
#define GG 100
#define AA 8400
#define TPB 256
#define NCH 33                         // ceil(8400/256) chunks per image
#define TKB 512                        // kB block size (8 waves)
#define BA (BB*AA)
#define NG (BB*GG)
#define PCAP 8416                      // positives cap (>= AA, cannot overflow)
#define GCAP 128                       // geo cap (provably <= 75 per gt)
#define SCAP (GG*10)                   // selection slots per image (g*10+k)

typedef __hip_bfloat16 bf16;

struct P {
  const void *outs, *labs, *ss;
  float4 *box4, *meta4, *gtb, *gtc;   // per-anchor box/meta; per-gt box/center
  float4 *cbox;                       // per-image compacted fg pred boxes
  uint32_t *cpk;                      // compacted packed (xc,yc,lvl)
  float *carea, *cpcc;                // compacted pred area / cls-cost
  int   *sel_a;                       // [BB][SCAP] selected anchor id, -1 empty
  float *sel_iou;                     // [BB][SCAP] its iou
  float *pb, *pf;                     // per-image BCE / fg partials
  int *gmax, *nfg, *chunkcnt, *ticket;
  float *out;
};

// runtime input-dtype detection: strides[0]==8.0
// f32 word 0x41000000 ; bf16 pair (8.0,8.0) 0x41004100
__device__ __forceinline__ int dtypeFlag(const void* ss){
  return (((const uint32_t*)ss)[0] == 0x41000000u) ? 1 : 0;
}
__device__ __forceinline__ float ld(const void* p, int i, int isf32){
  return isf32 ? ((const float*)p)[i] : __bfloat162float(((const bf16*)p)[i]);
}
// analytic anchor geometry (exact: ints + pow2 strides exact in f32/bf16)
__device__ __forceinline__ void ageom(int a, float& xc, float& yc, float& r){
  int x, y, s;
  if (a < 6400){ x = a % 80; y = a / 80; s = 8; }
  else if (a < 8000){ int q = a - 6400; x = q % 40; y = q / 40; s = 16; }
  else { int q = a - 8000; x = q % 20; y = q / 20; s = 32; }
  float fs = (float)s;
  xc = ((float)x + 0.5f) * fs;
  yc = ((float)y + 0.5f) * fs;
  r  = 2.5f * fs;
}
// pack integer center + level: xc(10) | yc(10)<<10 | lvl<<20
__device__ __forceinline__ uint32_t apack2(int a){
  int x, y, s, lvl;
  if (a < 6400){ x = a % 80; y = a / 80; s = 8; lvl = 0; }
  else if (a < 8000){ int q = a - 6400; x = q % 40; y = q / 40; s = 16; lvl = 1; }
  else { int q = a - 8000; x = q % 20; y = q / 20; s = 32; lvl = 2; }
  return (uint32_t)(x*s + s/2) | ((uint32_t)(y*s + s/2) << 10) | ((uint32_t)lvl << 20);
}
// exact inverse: packed -> anchor id
__device__ __forceinline__ int adecode(uint32_t u){
  int xi = u & 1023, yi = (u >> 10) & 1023, lvl = (int)(u >> 20);
  int sh = 3 + lvl, hf = 4 << lvl;
  int ax = (xi - hf) >> sh, ay = (yi - hf) >> sh;
  if (lvl == 0) return ay*80 + ax;
  if (lvl == 1) return 6400 + ay*40 + ax;
  return 8000 + ay*20 + ax;
}

// ---- kA: gt structs (self-computed) + per-anchor staging + fg + chunk count
// v8: cnt-zeroing removed (cnt array deleted); inits sel_a slots to -1 and
// the kC ticket instead.
__global__ __launch_bounds__(TPB) void kA(P p){
  __shared__ float4 s_gtb[GG], s_gtc[GG];
  __shared__ float s_o[TPB*6];
  __shared__ int s_w[4];
  __shared__ int s_ng;
  int t = threadIdx.x;
  int c = blockIdx.x, b = blockIdx.y;
  int isf = dtypeFlag(p.ss);
  if (t == 0) s_ng = 0;
  if (c == 0 && b == 0 && t == 0) *p.ticket = 0;   // for fused kC finisher
  {
    int s = c*TPB + t;
    if (s < SCAP) p.sel_a[b*SCAP + s] = -1;        // empty slot marker
  }
  int nel = min(TPB*6, AA*6 - c*(TPB*6));      // floats in this chunk
  if (isf){
    const float4* src = (const float4*)((const float*)p.outs + (size_t)b*AA*6 + (size_t)c*(TPB*6));
    float4* dst = (float4*)s_o;
    for (int i = t; i < nel/4; i += TPB) dst[i] = src[i];
  } else {
    const uint4* src = (const uint4*)((const bf16*)p.outs + (size_t)b*AA*6 + (size_t)c*(TPB*6));
    for (int i = t; i < nel/8; i += TPB){
      uint4 u = src[i];
      int o = i*8;
      s_o[o+0]=__uint_as_float(u.x<<16); s_o[o+1]=__uint_as_float(u.x&0xffff0000u);
      s_o[o+2]=__uint_as_float(u.y<<16); s_o[o+3]=__uint_as_float(u.y&0xffff0000u);
      s_o[o+4]=__uint_as_float(u.z<<16); s_o[o+5]=__uint_as_float(u.z&0xffff0000u);
      s_o[o+6]=__uint_as_float(u.w<<16); s_o[o+7]=__uint_as_float(u.w&0xffff0000u);
    }
  }
  __syncthreads();
  if (t < GG){
    int i = b*GG + t;
    float l0 = ld(p.labs, i*5  , isf);
    float gcx= ld(p.labs, i*5+1, isf);
    float gcy= ld(p.labs, i*5+2, isf);
    float gw = ld(p.labs, i*5+3, isf);
    float gh = ld(p.labs, i*5+4, isf);
    int valid = (l0+gcx+gcy+gw+gh) > 0.f;
    float4 vb = make_float4(gcx-gw*0.5f, gcy-gh*0.5f, gcx+gw*0.5f, gcy+gh*0.5f);
    float4 vc = make_float4(gcx, gcy, gw*gh, valid ? 1.f : 0.f);
    s_gtb[t] = vb; s_gtc[t] = vc;
    if (c == 0){ p.gtb[i] = vb; p.gtc[i] = vc; }
    if (valid) atomicMax(&s_ng, t+1);
  }
  __syncthreads();
  int ng = s_ng;
  if (c == 0 && t == 0) p.gmax[b] = ng;
  int a = c*TPB + t;
  int fg = 0;
  if (a < AA){
    float cx=s_o[t*6], cy=s_o[t*6+1], w=s_o[t*6+2], h=s_o[t*6+3], ob=s_o[t*6+4], cl=s_o[t*6+5];
    int idx = b*AA + a;
    p.box4[idx] = make_float4(cx-w*0.5f, cy-h*0.5f, cx+w*0.5f, cy+h*0.5f);
    float so = 1.f/(1.f+expf(-ob));
    float sc = 1.f/(1.f+expf(-cl));
    float pcc = -logf(sqrtf(sc*so) + 1e-9f);
    float xc, yc, r; ageom(a, xc, yc, r);
    for (int g = 0; g < ng; ++g){
      float4 gb = s_gtb[g], gc = s_gtc[g];
      bool inb = (xc>gb.x)&&(xc<gb.z)&&(yc>gb.y)&&(yc<gb.w);
      bool inc = (fabsf(xc-gc.x)<r)&&(fabsf(yc-gc.y)<r);
      fg |= (gc.w != 0.f) && (inb||inc);
    }
    p.meta4[idx] = make_float4(w*h, pcc, fg ? 1.f : 0.f, cl);
  }
  int lane = t & 63, wid = t >> 6;
  unsigned long long m = __ballot(fg);
  if (lane == 0) s_w[wid] = __popcll(m);
  __syncthreads();
  if (t == 0) p.chunkcnt[b*NCH + c] = s_w[0]+s_w[1]+s_w[2]+s_w[3];
}

// ---- kE: parallel order-preserving fg compaction (one block per chunk) -----
__global__ __launch_bounds__(TPB) void kE(P p){
  __shared__ int s_off;
  __shared__ int s_w[4];
  int t = threadIdx.x, c = blockIdx.x, b = blockIdx.y;
  int lane = t & 63, wid = t >> 6;
  if (wid == 0){
    int v = (lane < c) ? p.chunkcnt[b*NCH + lane] : 0;   // c <= 32 < 64 lanes
#pragma unroll
    for (int off=32; off; off>>=1) v += __shfl_xor(v, off);
    if (lane == 0) s_off = v;
  }
  int a = c*TPB + t;
  float4 mt = make_float4(0,0,0,0);
  int fg = 0;
  if (a < AA){ mt = p.meta4[b*AA+a]; fg = (mt.z != 0.f) ? 1 : 0; }
  unsigned long long m = __ballot(fg);
  int rank = __popcll(m & ((1ull<<lane)-1ull));
  if (lane == 0) s_w[wid] = __popcll(m);
  __syncthreads();
  int off = s_off;
  for (int w2 = 0; w2 < wid; ++w2) off += s_w[w2];
  if (fg){
    int pos = off + rank;
    p.cbox [b*AA+pos] = p.box4[b*AA+a];
    p.cpk  [b*AA+pos] = apack2(a);
    p.carea[b*AA+pos] = mt.x;
    p.cpcc [b*AA+pos] = mt.y;
  }
  if (c == NCH-1 && t == 0)
    p.nfg[b] = s_off + s_w[0]+s_w[1]+s_w[2]+s_w[3];
}

// ---- kB: per-(b,g) dyn_k + selection -------------------------------------
// v6 core (unchanged, passed absmax 0 r5/r6/r7): COMPACT-THEN-SELECT with
// deterministic slot output sel_a/sel_iou[b][g*10+k]; no global atomics.
__global__ __launch_bounds__(TKB) void kB(P p){
  __shared__ float s_pos[PCAP];
  __shared__ float s_gcost[GCAP];
  __shared__ int   s_gpos[GCAP];
  __shared__ int   s_pcnt, s_gcnt;
  int t = threadIdx.x;
  int lane = t & 63, wid = t >> 6;
  int item = blockIdx.x;
  int b = item / GG, g = item - b*GG;       // balanced across XCDs
  if (t == 0){ s_pcnt = 0; s_gcnt = 0; }
  float4 gc = p.gtc[b*GG+g];
  if (gc.w == 0.f) return;                  // uniform exit, pre-barrier
  float4 gb = p.gtb[b*GG+g];
  float glx=gb.x, gly=gb.y, ghx=gb.z, ghy=gb.w, gcx=gc.x, gcy=gc.y, ga=gc.z;
  int base = b*AA;
  int nfg = p.nfg[b];
  unsigned long long lmlt = (1ull<<lane) - 1ull;
  __syncthreads();                          // s_pcnt/s_gcnt init visible

  // main screen: ~30 VALU/pair, 20B/pair steady; heavy math only on hits
  int nIt = (nfg + TKB - 1) / TKB;
  for (int it = 0; it < nIt; ++it){
    int pos = it*TKB + t;
    bool vld = pos < nfg;
    bool ovl = false, geo = false;
    float v = 0.f, cst = 0.f;
    if (vld){
      uint32_t u = p.cpk[base+pos];
      float xc = (float)(u & 1023u), yc = (float)((u>>10)&1023u);
      float r  = (float)(20u << (u>>20));
      bool inb = (xc>glx)&&(xc<ghx)&&(yc>gly)&&(yc<ghy);
      geo = inb && (fabsf(xc-gcx)<r) && (fabsf(yc-gcy)<r);
      float4 bx = p.cbox[base+pos];
      float tlx=fmaxf(glx,bx.x), tly=fmaxf(gly,bx.y);
      float brx=fminf(ghx,bx.z), bry=fminf(ghy,bx.w);
      float iw=brx-tlx, ih=bry-tly;
      ovl = (iw>0.f)&&(ih>0.f);
      if (ovl | geo){
        float area = p.carea[base+pos];
        float inter = fmaxf(iw,0.f)*fmaxf(ih,0.f);
        v = inter/(ga + area - inter + 1e-12f);
        if (geo) cst = p.cpcc[base+pos] + 3.f*(-logf(v+1e-8f));
      }
    }
    unsigned long long m1 = __ballot(ovl);
    if (m1){
      int ldr = (int)(__ffsll(m1)-1);
      int off;
      if (lane == ldr) off = atomicAdd(&s_pcnt, __popcll(m1));
      off = __shfl(off, ldr);
      if (ovl) s_pos[off + __popcll(m1 & lmlt)] = v;
    }
    unsigned long long m2 = __ballot(geo);
    if (m2){
      int ldr = (int)(__ffsll(m2)-1);
      int off;
      if (lane == ldr) off = atomicAdd(&s_gcnt, __popcll(m2));
      off = __shfl(off, ldr);
      if (geo){
        int q = off + __popcll(m2 & lmlt);
        s_gcost[q] = cst; s_gpos[q] = pos;
      }
    }
  }
  __syncthreads();
  if (wid) return;                          // 7 waves done; wave 0 selects

  int pcnt = s_pcnt, gcnt = s_gcnt;         // gcnt <= 75 < GCAP

  // dk: top-10 positives by pop-extraction over s_pos (values only;
  // descending add order == jnp top_k sum order; zeros add exactly 0)
  float lmax = -1.f;
  for (int i = lane; i < pcnt; i += 64) lmax = fmaxf(lmax, s_pos[i]);
  float sum = 0.f;
  for (int k = 0; k < 10; ++k){
    float gv = lmax;
#pragma unroll
    for (int off=32; off; off>>=1) gv = fmaxf(gv, __shfl_xor(gv, off));
    if (gv <= 0.f) break;
    sum += gv;
    unsigned long long ms = __ballot(lmax == gv);
    if ((int)(__ffsll(ms)-1) == lane){      // unique owner: remove 1 instance
      bool fnd = false; float nl = -1.f;
      for (int i = lane; i < pcnt; i += 64){
        float vv = s_pos[i];
        if (!fnd && vv == gv){ fnd = true; vv = -1.f; s_pos[i] = vv; }
        nl = fmaxf(nl, vv);
      }
      lmax = nl;
    }
  }
  int dk = (int)sum; if (dk<1) dk=1; if (dk>10) dk=10;

  // selection among geo (<=2 entries/lane; all geo < all non-geo cost)
  float c0=3.0e38f, c1=3.0e38f; int p0=0x7fffffff, p1=0x7fffffff;
  if (lane < gcnt){ c0 = s_gcost[lane]; p0 = s_gpos[lane]; }
  if (lane+64 < gcnt){ c1 = s_gcost[lane+64]; p1 = s_gpos[lane+64]; }
  if (c1 < c0 || (c1==c0 && p1<p0)){
    float tc=c0; c0=c1; c1=tc; int tp=p0; p0=p1; p1=tp;
  }
  int mysel = -1, take = 0;
  for (int k = 0; k < dk; ++k){
    float gv=c0; int gi=p0;
#pragma unroll
    for (int off=32; off; off>>=1){
      float ov=__shfl_xor(gv,off); int oi=__shfl_xor(gi,off);
      if (ov<gv || (ov==gv && oi<gi)){ gv=ov; gi=oi; }
    }
    if (gv >= 2.9e38f) break;               // geo exhausted
    if (lane == k) mysel = gi;
    take++;
    if (c0==gv && p0==gi){ c0=c1; p0=p1; c1=3.0e38f; p1=0x7fffffff; }
  }

  // rare fallback: need (dk-take) non-geo picks; exact k-th smallest via
  // repeated rescan excluding previous picks by strict lex >
  float lastc = -3.0e38f; int lastp = -1;
  for (int k = take; k < dk; ++k){
    float bc = 3.0e38f; int bp = 0x7fffffff;
    int n64 = (nfg + 63) >> 6;
    for (int it = 0; it < n64; ++it){
      int pos = (it<<6) + lane;
      if (pos < nfg){
        uint32_t u = p.cpk[base+pos];
        float xc = (float)(u & 1023u), yc = (float)((u>>10)&1023u);
        float r  = (float)(20u << (u>>20));
        bool inb = (xc>glx)&&(xc<ghx)&&(yc>gly)&&(yc<ghy);
        bool geo2 = inb && (fabsf(xc-gcx)<r) && (fabsf(yc-gcy)<r);
        if (!geo2){
          float4 bx = p.cbox[base+pos];
          float tlx=fmaxf(glx,bx.x), tly=fmaxf(gly,bx.y);
          float brx=fminf(ghx,bx.z), bry=fminf(ghy,bx.w);
          float iw=fmaxf(brx-tlx,0.f), ih=fmaxf(bry-tly,0.f);
          float inter=iw*ih;
          float area = p.carea[base+pos];
          float v = inter/(ga + area - inter + 1e-12f);
          float cst = p.cpcc[base+pos] + 3.f*(-logf(v+1e-8f)) + 100000.f;
          bool gt = (cst > lastc) || (cst == lastc && pos > lastp);
          bool lt = (cst < bc)   || (cst == bc   && pos < bp);
          if (gt && lt){ bc = cst; bp = pos; }
        }
      }
    }
#pragma unroll
    for (int off=32; off; off>>=1){
      float ov=__shfl_xor(bc,off); int oi=__shfl_xor(bp,off);
      if (ov<bc || (ov==bc && oi<bp)){ bc=ov; bp=oi; }
    }
    if (bc >= 2.9e38f) break;               // candidates exhausted
    if (lane == k) mysel = bp;
    lastc = bc; lastp = bp;
  }

  if (mysel >= 0){                          // lanes 0..dk-1 hold selections
    int pos = mysel;
    float4 bx = p.cbox[base+pos];
    float area = p.carea[base+pos];
    int a = adecode(p.cpk[base+pos]);
    float tlx=fmaxf(glx,bx.x), tly=fmaxf(gly,bx.y);
    float brx=fminf(ghx,bx.z), bry=fminf(ghy,bx.w);
    float iw=fmaxf(brx-tlx,0.f), ih=fmaxf(bry-tly,0.f);
    float inter=iw*ih;
    float iou=inter/(ga + area - inter + 1e-12f);
    int slot = b*SCAP + g*10 + lane;        // deterministic, no atomics
    p.sel_a [slot] = a;
    p.sel_iou[slot] = iou;
  }
}

// ---- kC: selection-list conflict resolution + BCE + fused finalize --------
// v9: r7's O(ns^2) serial LDS owner-scan (375us!) replaced by a direct-map
// LDS count table s_cnt[AA] (33.6KB): pass1 = one LDS atomicAdd per slot,
// pass2 = cgt lookup; cgt==1 -> unique slot is trivially the owner (use its
// recorded iou, bit-exact); cgt>1 (rare) -> owner = first slot holding a
// (scan only then), recompute verbatim. Same cnt values / exactly-once
// ownership / per-thread slot-stride sum order as r7 (passed absmax 0).
__global__ __launch_bounds__(TPB) void kC(P p){
  __shared__ int   s_cnt[AA];
  __shared__ int   s_a[SCAP];
  __shared__ float s_iou[SCAP];
  __shared__ float s_b[4], s_f[4];
  __shared__ int s_last;
  int t = threadIdx.x, b = blockIdx.x;
  int ng = p.gmax[b];
  int ns = ng*10;                           // used slot range
  for (int i = t; i < AA; i += TPB) s_cnt[i] = 0;
  for (int i = t; i < ns; i += TPB){
    s_a[i]   = p.sel_a [b*SCAP + i];
    s_iou[i] = p.sel_iou[b*SCAP + i];
  }
  __syncthreads();
  for (int i = t; i < ns; i += TPB){
    int a = s_a[i];
    if (a >= 0) atomicAdd(&s_cnt[a], 1);
  }
  __syncthreads();
  float bce = 0.f, fgv = 0.f;
  for (int i = t; i < ns; i += TPB){
    int a = s_a[i];
    if (a < 0) continue;
    int cgt = s_cnt[a];
    float iouv;
    if (cgt == 1){
      iouv = s_iou[i];                      // unique slot == owner
    } else {
      bool owner = true;                    // rare: first-slot ownership
      for (int j = 0; j < i; ++j) if (s_a[j] == a){ owner = false; break; }
      if (!owner) continue;
      // verbatim conflicted-anchor recompute (first-index argmin)
      float4 mtc = p.meta4[b*AA + a];
      float4 bx = p.box4[b*AA + a];
      float xc,yc,r; ageom(a,xc,yc,r);
      float best=3.9e38f, biou=0.f;
      for (int g2=0; g2<ng; ++g2){
        float4 gbb = p.gtb[b*GG+g2], gcc = p.gtc[b*GG+g2];
        float cost, iou2 = 0.f;
        if (gcc.w != 0.f){
          float tlx=fmaxf(gbb.x,bx.x), tly=fmaxf(gbb.y,bx.y);
          float brx=fminf(gbb.z,bx.z), bry=fminf(gbb.w,bx.w);
          float iw=fmaxf(brx-tlx,0.f), ih=fmaxf(bry-tly,0.f);
          float inter=iw*ih;
          iou2 = inter/(gcc.z + mtc.x - inter + 1e-12f);
          bool inb=(xc>gbb.x)&&(xc<gbb.z)&&(yc>gbb.y)&&(yc<gbb.w);
          bool inc=(fabsf(xc-gcc.x)<r)&&(fabsf(yc-gcc.y)<r);
          cost = mtc.y + 3.f*(-logf(iou2+1e-8f)) + ((inb&&inc)?0.f:100000.f);
        } else cost = 1e9f;
        if (cost < best){ best=cost; biou=iou2; }
      }
      iouv = biou;
    }
    float z = p.meta4[b*AA + a].w;
    float e = expf(-fabsf(z));
    float spz = fmaxf(z,0.f)+log1pf(e);
    float spn = fmaxf(-z,0.f)+log1pf(e);
    bce += iouv*spn + (1.f-iouv)*spz;
    fgv += 1.f;
  }
  // block reduce -> per-image partials
  int lane = t & 63, wid = t >> 6;
#pragma unroll
  for (int off=32; off; off>>=1){
    bce += __shfl_xor(bce, off);
    fgv += __shfl_xor(fgv, off);
  }
  if (lane==0){ s_b[wid]=bce; s_f[wid]=fgv; }
  __syncthreads();
  if (t==0){
    p.pb[b] = s_b[0]+s_b[1]+s_b[2]+s_b[3];
    p.pf[b] = s_f[0]+s_f[1]+s_f[2]+s_f[3];
    __threadfence();                       // publish partials (device scope)
    int old = atomicAdd(p.ticket, 1);
    s_last = (old == BB-1) ? 1 : 0;
  }
  __syncthreads();
  if (s_last && t < 64){
    __threadfence();                       // acquire all partials
    float sb = (t < BB) ? p.pb[t] : 0.f;
    float sf = (t < BB) ? p.pf[t] : 0.f;
#pragma unroll
    for (int off=32; off; off>>=1){
      sb += __shfl_xor(sb, off);
      sf += __shfl_xor(sf, off);
    }
    if (t==0) p.out[0] = sb / fmaxf(sf, 1.f);
  }
}

extern "C" void kernel_launch(void* const* d_in, const int* in_sizes, int n_in,
                              void* d_out, int out_size, void* d_ws, size_t ws_size,
                              hipStream_t stream) {
  P p;
  p.outs = d_in[0];
  p.labs = d_in[1];
  p.ss   = d_in[4];
  char* w = (char*)d_ws;
  p.box4  = (float4*)w; w += (size_t)BA*sizeof(float4);
  p.meta4 = (float4*)w; w += (size_t)BA*sizeof(float4);
  p.cbox  = (float4*)w; w += (size_t)BA*sizeof(float4);
  p.gtb   = (float4*)w; w += (size_t)NG*sizeof(float4);
  p.gtc   = (float4*)w; w += (size_t)NG*sizeof(float4);
  p.cpk   = (uint32_t*)w; w += (size_t)BA*sizeof(uint32_t);
  p.carea = (float*)w;  w += (size_t)BA*sizeof(float);
  p.cpcc  = (float*)w;  w += (size_t)BA*sizeof(float);
  p.sel_a = (int*)w;    w += (size_t)BB*SCAP*sizeof(int);
  p.sel_iou=(float*)w;  w += (size_t)BB*SCAP*sizeof(float);
  p.gmax  = (int*)w;    w += (size_t)BB*sizeof(int);
  p.nfg   = (int*)w;    w += (size_t)BB*sizeof(int);
  p.chunkcnt = (int*)w; w += (size_t)BB*NCH*sizeof(int);
  p.pb    = (float*)w;  w += (size_t)BB*sizeof(float);
  p.pf    = (float*)w;  w += (size_t)BB*sizeof(float);
  p.ticket= (int*)w;    w += sizeof(int);
  p.out   = (float*)d_out;

  kA<<<dim3(NCH, BB), TPB, 0, stream>>>(p);
  kE<<<dim3(NCH, BB), TPB, 0, stream>>>(p);
  kB<<<BB*GG, TKB, 0, stream>>>(p);
  kC<<<BB, TPB, 0, stream>>>(p);
}

// Round 9
// 189.956 us; speedup vs baseline: 2.6050x; 2.1988x over previous
//
#include <hip/hip_runtime.h>
#include <hip/hip_bf16.h>
#include <stdint.h>

#define BB 32
#define GG 100
#define AA 8400
#define TPB 256
#define NCH 33                         // ceil(8400/256) chunks per image
#define TKB 512                        // kB block size (8 waves)
#define BA (BB*AA)
#define NG (BB*GG)
#define NB2 (BB*GG)                    // kR blocks / partial count
#define PCAP 8416                      // positives cap (>= AA, cannot overflow)
#define GCAP 128                       // geo cap (provably <= 75 per gt)
#define SCAP (GG*10)                   // selection slots per image (g*10+k)

typedef __hip_bfloat16 bf16;

struct P {
  const void *outs, *labs, *ss;
  float4 *box4, *meta4, *gtb, *gtc;   // per-anchor box/meta; per-gt box/center
  float4 *cbox;                       // per-image compacted fg pred boxes
  uint32_t *cpk;                      // compacted packed (xc,yc,lvl)
  float *carea, *cpcc;                // compacted pred area / cls-cost
  int   *sel_a;                       // [BB][SCAP] selected anchor id, -1 empty
  float *sel_iou;                     // [BB][SCAP] its iou
  int   *cnt, *own;                   // per-anchor selection count / min slot
  float *pb, *pf;                     // per-(b,g) BCE / fg partials
  int *gmax, *nfg, *chunkcnt;
  float *out;
};

// runtime input-dtype detection: strides[0]==8.0
// f32 word 0x41000000 ; bf16 pair (8.0,8.0) 0x41004100
__device__ __forceinline__ int dtypeFlag(const void* ss){
  return (((const uint32_t*)ss)[0] == 0x41000000u) ? 1 : 0;
}
__device__ __forceinline__ float ld(const void* p, int i, int isf32){
  return isf32 ? ((const float*)p)[i] : __bfloat162float(((const bf16*)p)[i]);
}
// analytic anchor geometry (exact: ints + pow2 strides exact in f32/bf16)
__device__ __forceinline__ void ageom(int a, float& xc, float& yc, float& r){
  int x, y, s;
  if (a < 6400){ x = a % 80; y = a / 80; s = 8; }
  else if (a < 8000){ int q = a - 6400; x = q % 40; y = q / 40; s = 16; }
  else { int q = a - 8000; x = q % 20; y = q / 20; s = 32; }
  float fs = (float)s;
  xc = ((float)x + 0.5f) * fs;
  yc = ((float)y + 0.5f) * fs;
  r  = 2.5f * fs;
}
// pack integer center + level: xc(10) | yc(10)<<10 | lvl<<20
__device__ __forceinline__ uint32_t apack2(int a){
  int x, y, s, lvl;
  if (a < 6400){ x = a % 80; y = a / 80; s = 8; lvl = 0; }
  else if (a < 8000){ int q = a - 6400; x = q % 40; y = q / 40; s = 16; lvl = 1; }
  else { int q = a - 8000; x = q % 20; y = q / 20; s = 32; lvl = 2; }
  return (uint32_t)(x*s + s/2) | ((uint32_t)(y*s + s/2) << 10) | ((uint32_t)lvl << 20);
}
// exact inverse: packed -> anchor id
__device__ __forceinline__ int adecode(uint32_t u){
  int xi = u & 1023, yi = (u >> 10) & 1023, lvl = (int)(u >> 20);
  int sh = 3 + lvl, hf = 4 << lvl;
  int ax = (xi - hf) >> sh, ay = (yi - hf) >> sh;
  if (lvl == 0) return ay*80 + ax;
  if (lvl == 1) return 6400 + ay*40 + ax;
  return 8000 + ay*20 + ax;
}

// ---- kA: gt structs (self-computed) + per-anchor staging + fg + chunk count
// v10: restores cnt=0 init (r6 regime) + adds own=INT_MAX init; sel_a -1 init.
__global__ __launch_bounds__(TPB) void kA(P p){
  __shared__ float4 s_gtb[GG], s_gtc[GG];
  __shared__ float s_o[TPB*6];
  __shared__ int s_w[4];
  __shared__ int s_ng;
  int t = threadIdx.x;
  int c = blockIdx.x, b = blockIdx.y;
  int isf = dtypeFlag(p.ss);
  if (t == 0) s_ng = 0;
  {
    int s = c*TPB + t;
    if (s < SCAP) p.sel_a[b*SCAP + s] = -1;        // empty slot marker
  }
  int nel = min(TPB*6, AA*6 - c*(TPB*6));      // floats in this chunk
  if (isf){
    const float4* src = (const float4*)((const float*)p.outs + (size_t)b*AA*6 + (size_t)c*(TPB*6));
    float4* dst = (float4*)s_o;
    for (int i = t; i < nel/4; i += TPB) dst[i] = src[i];
  } else {
    const uint4* src = (const uint4*)((const bf16*)p.outs + (size_t)b*AA*6 + (size_t)c*(TPB*6));
    for (int i = t; i < nel/8; i += TPB){
      uint4 u = src[i];
      int o = i*8;
      s_o[o+0]=__uint_as_float(u.x<<16); s_o[o+1]=__uint_as_float(u.x&0xffff0000u);
      s_o[o+2]=__uint_as_float(u.y<<16); s_o[o+3]=__uint_as_float(u.y&0xffff0000u);
      s_o[o+4]=__uint_as_float(u.z<<16); s_o[o+5]=__uint_as_float(u.z&0xffff0000u);
      s_o[o+6]=__uint_as_float(u.w<<16); s_o[o+7]=__uint_as_float(u.w&0xffff0000u);
    }
  }
  __syncthreads();
  if (t < GG){
    int i = b*GG + t;
    float l0 = ld(p.labs, i*5  , isf);
    float gcx= ld(p.labs, i*5+1, isf);
    float gcy= ld(p.labs, i*5+2, isf);
    float gw = ld(p.labs, i*5+3, isf);
    float gh = ld(p.labs, i*5+4, isf);
    int valid = (l0+gcx+gcy+gw+gh) > 0.f;
    float4 vb = make_float4(gcx-gw*0.5f, gcy-gh*0.5f, gcx+gw*0.5f, gcy+gh*0.5f);
    float4 vc = make_float4(gcx, gcy, gw*gh, valid ? 1.f : 0.f);
    s_gtb[t] = vb; s_gtc[t] = vc;
    if (c == 0){ p.gtb[i] = vb; p.gtc[i] = vc; }
    if (valid) atomicMax(&s_ng, t+1);
  }
  __syncthreads();
  int ng = s_ng;
  if (c == 0 && t == 0) p.gmax[b] = ng;
  int a = c*TPB + t;
  int fg = 0;
  if (a < AA){
    float cx=s_o[t*6], cy=s_o[t*6+1], w=s_o[t*6+2], h=s_o[t*6+3], ob=s_o[t*6+4], cl=s_o[t*6+5];
    int idx = b*AA + a;
    p.box4[idx] = make_float4(cx-w*0.5f, cy-h*0.5f, cx+w*0.5f, cy+h*0.5f);
    float so = 1.f/(1.f+expf(-ob));
    float sc = 1.f/(1.f+expf(-cl));
    float pcc = -logf(sqrtf(sc*so) + 1e-9f);
    float xc, yc, r; ageom(a, xc, yc, r);
    for (int g = 0; g < ng; ++g){
      float4 gb = s_gtb[g], gc = s_gtc[g];
      bool inb = (xc>gb.x)&&(xc<gb.z)&&(yc>gb.y)&&(yc<gb.w);
      bool inc = (fabsf(xc-gc.x)<r)&&(fabsf(yc-gc.y)<r);
      fg |= (gc.w != 0.f) && (inb||inc);
    }
    p.meta4[idx] = make_float4(w*h, pcc, fg ? 1.f : 0.f, cl);
    p.cnt[idx] = 0;
    p.own[idx] = 0x7fffffff;
  }
  int lane = t & 63, wid = t >> 6;
  unsigned long long m = __ballot(fg);
  if (lane == 0) s_w[wid] = __popcll(m);
  __syncthreads();
  if (t == 0) p.chunkcnt[b*NCH + c] = s_w[0]+s_w[1]+s_w[2]+s_w[3];
}

// ---- kE: parallel order-preserving fg compaction (one block per chunk) -----
__global__ __launch_bounds__(TPB) void kE(P p){
  __shared__ int s_off;
  __shared__ int s_w[4];
  int t = threadIdx.x, c = blockIdx.x, b = blockIdx.y;
  int lane = t & 63, wid = t >> 6;
  if (wid == 0){
    int v = (lane < c) ? p.chunkcnt[b*NCH + lane] : 0;   // c <= 32 < 64 lanes
#pragma unroll
    for (int off=32; off; off>>=1) v += __shfl_xor(v, off);
    if (lane == 0) s_off = v;
  }
  int a = c*TPB + t;
  float4 mt = make_float4(0,0,0,0);
  int fg = 0;
  if (a < AA){ mt = p.meta4[b*AA+a]; fg = (mt.z != 0.f) ? 1 : 0; }
  unsigned long long m = __ballot(fg);
  int rank = __popcll(m & ((1ull<<lane)-1ull));
  if (lane == 0) s_w[wid] = __popcll(m);
  __syncthreads();
  int off = s_off;
  for (int w2 = 0; w2 < wid; ++w2) off += s_w[w2];
  if (fg){
    int pos = off + rank;
    p.cbox [b*AA+pos] = p.box4[b*AA+a];
    p.cpk  [b*AA+pos] = apack2(a);
    p.carea[b*AA+pos] = mt.x;
    p.cpcc [b*AA+pos] = mt.y;
  }
  if (c == NCH-1 && t == 0)
    p.nfg[b] = s_off + s_w[0]+s_w[1]+s_w[2]+s_w[3];
}

// ---- kB: per-(b,g) dyn_k + selection -------------------------------------
// v6 core (unchanged, passed absmax 0 r5-r8). v10 delta: selections also do
// atomicAdd(cnt[a]) + atomicMin(own[a], slot) -- atomicMin is commutative,
// so ownership (min slot per anchor) is deterministic regardless of timing.
__global__ __launch_bounds__(TKB) void kB(P p){
  __shared__ float s_pos[PCAP];
  __shared__ float s_gcost[GCAP];
  __shared__ int   s_gpos[GCAP];
  __shared__ int   s_pcnt, s_gcnt;
  int t = threadIdx.x;
  int lane = t & 63, wid = t >> 6;
  int item = blockIdx.x;
  int b = item / GG, g = item - b*GG;       // balanced across XCDs
  if (t == 0){ s_pcnt = 0; s_gcnt = 0; }
  float4 gc = p.gtc[b*GG+g];
  if (gc.w == 0.f) return;                  // uniform exit, pre-barrier
  float4 gb = p.gtb[b*GG+g];
  float glx=gb.x, gly=gb.y, ghx=gb.z, ghy=gb.w, gcx=gc.x, gcy=gc.y, ga=gc.z;
  int base = b*AA;
  int nfg = p.nfg[b];
  unsigned long long lmlt = (1ull<<lane) - 1ull;
  __syncthreads();                          // s_pcnt/s_gcnt init visible

  // main screen: ~30 VALU/pair, 20B/pair steady; heavy math only on hits
  int nIt = (nfg + TKB - 1) / TKB;
  for (int it = 0; it < nIt; ++it){
    int pos = it*TKB + t;
    bool vld = pos < nfg;
    bool ovl = false, geo = false;
    float v = 0.f, cst = 0.f;
    if (vld){
      uint32_t u = p.cpk[base+pos];
      float xc = (float)(u & 1023u), yc = (float)((u>>10)&1023u);
      float r  = (float)(20u << (u>>20));
      bool inb = (xc>glx)&&(xc<ghx)&&(yc>gly)&&(yc<ghy);
      geo = inb && (fabsf(xc-gcx)<r) && (fabsf(yc-gcy)<r);
      float4 bx = p.cbox[base+pos];
      float tlx=fmaxf(glx,bx.x), tly=fmaxf(gly,bx.y);
      float brx=fminf(ghx,bx.z), bry=fminf(ghy,bx.w);
      float iw=brx-tlx, ih=bry-tly;
      ovl = (iw>0.f)&&(ih>0.f);
      if (ovl | geo){
        float area = p.carea[base+pos];
        float inter = fmaxf(iw,0.f)*fmaxf(ih,0.f);
        v = inter/(ga + area - inter + 1e-12f);
        if (geo) cst = p.cpcc[base+pos] + 3.f*(-logf(v+1e-8f));
      }
    }
    unsigned long long m1 = __ballot(ovl);
    if (m1){
      int ldr = (int)(__ffsll(m1)-1);
      int off;
      if (lane == ldr) off = atomicAdd(&s_pcnt, __popcll(m1));
      off = __shfl(off, ldr);
      if (ovl) s_pos[off + __popcll(m1 & lmlt)] = v;
    }
    unsigned long long m2 = __ballot(geo);
    if (m2){
      int ldr = (int)(__ffsll(m2)-1);
      int off;
      if (lane == ldr) off = atomicAdd(&s_gcnt, __popcll(m2));
      off = __shfl(off, ldr);
      if (geo){
        int q = off + __popcll(m2 & lmlt);
        s_gcost[q] = cst; s_gpos[q] = pos;
      }
    }
  }
  __syncthreads();
  if (wid) return;                          // 7 waves done; wave 0 selects

  int pcnt = s_pcnt, gcnt = s_gcnt;         // gcnt <= 75 < GCAP

  // dk: top-10 positives by pop-extraction over s_pos (values only;
  // descending add order == jnp top_k sum order; zeros add exactly 0)
  float lmax = -1.f;
  for (int i = lane; i < pcnt; i += 64) lmax = fmaxf(lmax, s_pos[i]);
  float sum = 0.f;
  for (int k = 0; k < 10; ++k){
    float gv = lmax;
#pragma unroll
    for (int off=32; off; off>>=1) gv = fmaxf(gv, __shfl_xor(gv, off));
    if (gv <= 0.f) break;
    sum += gv;
    unsigned long long ms = __ballot(lmax == gv);
    if ((int)(__ffsll(ms)-1) == lane){      // unique owner: remove 1 instance
      bool fnd = false; float nl = -1.f;
      for (int i = lane; i < pcnt; i += 64){
        float vv = s_pos[i];
        if (!fnd && vv == gv){ fnd = true; vv = -1.f; s_pos[i] = vv; }
        nl = fmaxf(nl, vv);
      }
      lmax = nl;
    }
  }
  int dk = (int)sum; if (dk<1) dk=1; if (dk>10) dk=10;

  // selection among geo (<=2 entries/lane; all geo < all non-geo cost)
  float c0=3.0e38f, c1=3.0e38f; int p0=0x7fffffff, p1=0x7fffffff;
  if (lane < gcnt){ c0 = s_gcost[lane]; p0 = s_gpos[lane]; }
  if (lane+64 < gcnt){ c1 = s_gcost[lane+64]; p1 = s_gpos[lane+64]; }
  if (c1 < c0 || (c1==c0 && p1<p0)){
    float tc=c0; c0=c1; c1=tc; int tp=p0; p0=p1; p1=tp;
  }
  int mysel = -1, take = 0;
  for (int k = 0; k < dk; ++k){
    float gv=c0; int gi=p0;
#pragma unroll
    for (int off=32; off; off>>=1){
      float ov=__shfl_xor(gv,off); int oi=__shfl_xor(gi,off);
      if (ov<gv || (ov==gv && oi<gi)){ gv=ov; gi=oi; }
    }
    if (gv >= 2.9e38f) break;               // geo exhausted
    if (lane == k) mysel = gi;
    take++;
    if (c0==gv && p0==gi){ c0=c1; p0=p1; c1=3.0e38f; p1=0x7fffffff; }
  }

  // rare fallback: need (dk-take) non-geo picks; exact k-th smallest via
  // repeated rescan excluding previous picks by strict lex >
  float lastc = -3.0e38f; int lastp = -1;
  for (int k = take; k < dk; ++k){
    float bc = 3.0e38f; int bp = 0x7fffffff;
    int n64 = (nfg + 63) >> 6;
    for (int it = 0; it < n64; ++it){
      int pos = (it<<6) + lane;
      if (pos < nfg){
        uint32_t u = p.cpk[base+pos];
        float xc = (float)(u & 1023u), yc = (float)((u>>10)&1023u);
        float r  = (float)(20u << (u>>20));
        bool inb = (xc>glx)&&(xc<ghx)&&(yc>gly)&&(yc<ghy);
        bool geo2 = inb && (fabsf(xc-gcx)<r) && (fabsf(yc-gcy)<r);
        if (!geo2){
          float4 bx = p.cbox[base+pos];
          float tlx=fmaxf(glx,bx.x), tly=fmaxf(gly,bx.y);
          float brx=fminf(ghx,bx.z), bry=fminf(ghy,bx.w);
          float iw=fmaxf(brx-tlx,0.f), ih=fmaxf(bry-tly,0.f);
          float inter=iw*ih;
          float area = p.carea[base+pos];
          float v = inter/(ga + area - inter + 1e-12f);
          float cst = p.cpcc[base+pos] + 3.f*(-logf(v+1e-8f)) + 100000.f;
          bool gt = (cst > lastc) || (cst == lastc && pos > lastp);
          bool lt = (cst < bc)   || (cst == bc   && pos < bp);
          if (gt && lt){ bc = cst; bp = pos; }
        }
      }
    }
#pragma unroll
    for (int off=32; off; off>>=1){
      float ov=__shfl_xor(bc,off); int oi=__shfl_xor(bp,off);
      if (ov<bc || (ov==bc && oi<bp)){ bc=ov; bp=oi; }
    }
    if (bc >= 2.9e38f) break;               // candidates exhausted
    if (lane == k) mysel = bp;
    lastc = bc; lastp = bp;
  }

  if (mysel >= 0){                          // lanes 0..dk-1 hold selections
    int pos = mysel;
    float4 bx = p.cbox[base+pos];
    float area = p.carea[base+pos];
    int a = adecode(p.cpk[base+pos]);
    float tlx=fmaxf(glx,bx.x), tly=fmaxf(gly,bx.y);
    float brx=fminf(ghx,bx.z), bry=fminf(ghy,bx.w);
    float iw=fmaxf(brx-tlx,0.f), ih=fmaxf(bry-tly,0.f);
    float inter=iw*ih;
    float iou=inter/(ga + area - inter + 1e-12f);
    int slot = g*10 + lane;                 // deterministic slot id
    p.sel_a [b*SCAP + slot] = a;
    p.sel_iou[b*SCAP + slot] = iou;
    atomicAdd(&p.cnt[base+a], 1);
    atomicMin(&p.own[base+a], slot);        // commutative -> deterministic owner
  }
}

// ---- kR: per-(b,g) resolution + BCE partials (grid 3200, 1 wave) ----------
// v10: replaces r7/r8's 32-block kC (309-375us at ~0% VALU; small-grid
// consumer kernels are empirically cursed ~300us regardless of work) and
// r6's 66us full-scan kCD. Each block reads only ITS g's <=10 slots;
// owner <=> own[a]==slot (min-slot, == r7/r8 first-slot semantics, passed
// absmax 0); cgt==1 -> recorded iou (bit-exact); cgt>1 -> verbatim argmin
// recompute. Deterministic partial buckets per (b,g).
__global__ __launch_bounds__(64) void kR(P p){
  int lane = threadIdx.x;
  int item = blockIdx.x;
  int b = item / GG, g = item - b*GG;
  int base = b*AA;
  float bce = 0.f, fgv = 0.f;
  if (lane < 10){
    int slot = g*10 + lane;
    int a = p.sel_a[b*SCAP + slot];
    if (a >= 0 && p.own[base+a] == slot){   // this slot owns the anchor
      int cgt = p.cnt[base+a];
      float4 mtc = p.meta4[base+a];
      float iouv;
      if (cgt == 1){
        iouv = p.sel_iou[b*SCAP + slot];
      } else {
        // verbatim conflicted-anchor recompute (first-index argmin)
        float4 bx = p.box4[base+a];
        float xc,yc,r; ageom(a,xc,yc,r);
        int ng = p.gmax[b];
        float best=3.9e38f, biou=0.f;
        for (int g2=0; g2<ng; ++g2){
          float4 gbb = p.gtb[b*GG+g2], gcc = p.gtc[b*GG+g2];
          float cost, iou2 = 0.f;
          if (gcc.w != 0.f){
            float tlx=fmaxf(gbb.x,bx.x), tly=fmaxf(gbb.y,bx.y);
            float brx=fminf(gbb.z,bx.z), bry=fminf(gbb.w,bx.w);
            float iw=fmaxf(brx-tlx,0.f), ih=fmaxf(bry-tly,0.f);
            float inter=iw*ih;
            iou2 = inter/(gcc.z + mtc.x - inter + 1e-12f);
            bool inb=(xc>gbb.x)&&(xc<gbb.z)&&(yc>gbb.y)&&(yc<gbb.w);
            bool inc=(fabsf(xc-gcc.x)<r)&&(fabsf(yc-gcc.y)<r);
            cost = mtc.y + 3.f*(-logf(iou2+1e-8f)) + ((inb&&inc)?0.f:100000.f);
          } else cost = 1e9f;
          if (cost < best){ best=cost; biou=iou2; }
        }
        iouv = biou;
      }
      float z = mtc.w;
      float e = expf(-fabsf(z));
      float spz = fmaxf(z,0.f)+log1pf(e);
      float spn = fmaxf(-z,0.f)+log1pf(e);
      bce = iouv*spn + (1.f-iouv)*spz;
      fgv = 1.f;
    }
  }
#pragma unroll
  for (int off=32; off; off>>=1){
    bce += __shfl_xor(bce, off);
    fgv += __shfl_xor(fgv, off);
  }
  if (lane == 0){ p.pb[item] = bce; p.pf[item] = fgv; }
}

// ---- kD: reduce 3200 partials + finalize (1 block) -------------------------
__global__ __launch_bounds__(TPB) void kD(P p){
  int t = threadIdx.x;
  float sb=0.f, sf=0.f;
  for (int i = t; i < NB2; i += TPB){ sb += p.pb[i]; sf += p.pf[i]; }
#pragma unroll
  for (int off=32; off; off>>=1){
    sb += __shfl_xor(sb, off);
    sf += __shfl_xor(sf, off);
  }
  __shared__ float s_b[4], s_f[4];
  int lane = t & 63, wid = t >> 6;
  if (lane==0){ s_b[wid]=sb; s_f[wid]=sf; }
  __syncthreads();
  if (t==0){
    float tb=s_b[0]+s_b[1]+s_b[2]+s_b[3];
    float tf=s_f[0]+s_f[1]+s_f[2]+s_f[3];
    p.out[0] = tb / fmaxf(tf, 1.f);
  }
}

extern "C" void kernel_launch(void* const* d_in, const int* in_sizes, int n_in,
                              void* d_out, int out_size, void* d_ws, size_t ws_size,
                              hipStream_t stream) {
  P p;
  p.outs = d_in[0];
  p.labs = d_in[1];
  p.ss   = d_in[4];
  char* w = (char*)d_ws;
  p.box4  = (float4*)w; w += (size_t)BA*sizeof(float4);
  p.meta4 = (float4*)w; w += (size_t)BA*sizeof(float4);
  p.cbox  = (float4*)w; w += (size_t)BA*sizeof(float4);
  p.gtb   = (float4*)w; w += (size_t)NG*sizeof(float4);
  p.gtc   = (float4*)w; w += (size_t)NG*sizeof(float4);
  p.cpk   = (uint32_t*)w; w += (size_t)BA*sizeof(uint32_t);
  p.carea = (float*)w;  w += (size_t)BA*sizeof(float);
  p.cpcc  = (float*)w;  w += (size_t)BA*sizeof(float);
  p.sel_a = (int*)w;    w += (size_t)BB*SCAP*sizeof(int);
  p.sel_iou=(float*)w;  w += (size_t)BB*SCAP*sizeof(float);
  p.cnt   = (int*)w;    w += (size_t)BA*sizeof(int);
  p.own   = (int*)w;    w += (size_t)BA*sizeof(int);
  p.gmax  = (int*)w;    w += (size_t)BB*sizeof(int);
  p.nfg   = (int*)w;    w += (size_t)BB*sizeof(int);
  p.chunkcnt = (int*)w; w += (size_t)BB*NCH*sizeof(int);
  p.pb    = (float*)w;  w += (size_t)NB2*sizeof(float);
  p.pf    = (float*)w;  w += (size_t)NB2*sizeof(float);
  p.out   = (float*)d_out;

  kA<<<dim3(NCH, BB), TPB, 0, stream>>>(p);
  kE<<<dim3(NCH, BB), TPB, 0, stream>>>(p);
  kB<<<BB*GG, TKB, 0, stream>>>(p);
  kR<<<NB2, 64, 0, stream>>>(p);
  kD<<<1, TPB, 0, stream>>>(p);
}